// Round 7
// baseline (203.430 us; speedup 1.0000x reference)
//
#include <hip/hip_runtime.h>

#define NN 50000
#define SNEI 16
#define GB 782            // ceil(50000/64)

typedef unsigned short ushort_t;
typedef unsigned int uint_t;
typedef unsigned long long u64;
typedef __attribute__((ext_vector_type(8))) short bhalf8;
typedef __attribute__((ext_vector_type(4))) float facc4;
typedef __attribute__((ext_vector_type(4))) float f32x4;

__device__ __forceinline__ float b2f(uint_t u) {
    union { uint_t u; float f; } x; x.u = u << 16; return x.f;
}
__device__ __forceinline__ ushort_t f2b(float f) {
    union { float f; uint_t u; } x; x.f = f;
    return (ushort_t)((x.u + 0x7FFFu + ((x.u >> 16) & 1u)) >> 16);
}
__device__ __forceinline__ u64 pack4(float a, float b, float c, float d) {
    return (u64)f2b(a) | ((u64)f2b(b) << 16) | ((u64)f2b(c) << 32) | ((u64)f2b(d) << 48);
}

typedef const __attribute__((address_space(1))) void cglb_t;
typedef __attribute__((address_space(3))) void lds3_t;
__device__ __forceinline__ void gload16(const void* g, void* l) {
    __builtin_amdgcn_global_load_lds((cglb_t*)g, (lds3_t*)l, 16, 0, 0);
}

// ---------------------------------------------------------------------------
// One-time weight setup (unchanged layout from round 5/6).
// Fragment k-bijection: chunk (ks*8+nf)*64+lane; elem j of lane l holds
// W[k][c], k = ks*32 + (l>>4)*8 + j (16B-contig), c = nf*16 + (l&15).
// Layer-1 weights pre-multiplied by prepW: W'1 = prepW @ W1  [256,128].
// perm chunks: [L1: mp0{x|n} mp1{x|n}][L2: same] = 32768 chunks.
// ---------------------------------------------------------------------------
__global__ void permSetup(const float* __restrict__ prepW,
                          const float* __restrict__ Wx1, const float* __restrict__ Wn1,
                          const float* __restrict__ Wx2, const float* __restrict__ Wn2,
                          ushort_t* __restrict__ dst)
{
    int e = blockIdx.x * 256 + threadIdx.x;
    int q8 = e >> 3, j = e & 7;
    int layer = q8 >> 14;
    int qq = q8 & 16383;
    int mp = qq >> 13, isN = (qq >> 12) & 1, q = qq & 4095;
    int lane = q & 63, nf = (q >> 6) & 7, ks = q >> 9;
    int c = nf * 16 + (lane & 15);                 // [0,128)
    int k = ks * 32 + ((lane >> 4) << 3) + j;      // [0,256)
    float v;
    if (layer == 0) {
        const float* W1 = (isN ? Wn1 : Wx1) + mp * 16384 + (c >> 6) * 8192 + (c & 63);
        const float* pw = prepW + (size_t)k * 128;
        float s0 = 0.f, s1 = 0.f;
#pragma unroll 4
        for (int p = 0; p < 128; p += 2) {
            s0 += pw[p]     * W1[(size_t)p * 64];
            s1 += pw[p + 1] * W1[(size_t)(p + 1) * 64];
        }
        v = s0 + s1;
    } else {
        const float* W2 = (isN ? Wn2 : Wx2) + mp * 32768 + (c >> 6) * 16384 + (size_t)k * 64 + (c & 63);
        v = *W2;
    }
    dst[(size_t)q8 * 8 + j] = f2b(v);
}

// ---------------------------------------------------------------------------
// Dual-projection GEMM, K=256, X always fp32 (feats pitch 256, or out pitch
// 512 for layer 2 — re-read of just-written fp32 h1 slots, L3-resident).
// wave_n=0: relu(X@Wx) -> nt fp32 out x-slots at obase.
// wave_n=1: X@Wn -> nt bf16 P, sliced layout P[slice][node][32].
// Tile 64 rows x 128 cols/role, BK=64, 4 waves, 40KB LDS.
// LDS chunks: X [0,512) | Wx [512,1536) | Wn [1536,2560).
// ---------------------------------------------------------------------------
__global__ __launch_bounds__(256, 4)
void proj_gemm(const float* __restrict__ X, int xPitch, size_t xMpStr,
               const ushort_t* __restrict__ W, size_t wMpStr,
               float* __restrict__ out, size_t oMpStr, int obase,
               ushort_t* __restrict__ P, size_t PMpStr)
{
    __shared__ bhalf8 lds[2560];
    u64* l64 = (u64*)lds;
    const int tid = threadIdx.x;
    const int lane = tid & 63;
    const int wid = tid >> 6;
    const int wave_m = wid >> 1, wave_n = wid & 1;
    const int m0 = blockIdx.x * 64;
    const int mp = blockIdx.y;

    const float* Xp = X + (size_t)mp * xMpStr;
    const ushort_t* wx = W + (size_t)mp * wMpStr;
    const ushort_t* wn = wx + 4096 * 8;
    float* outp = out + (size_t)mp * oMpStr;
    ushort_t* Pp = P + (size_t)mp * PMpStr;

    facc4 acc[2][8];
    const facc4 z = {0.f, 0.f, 0.f, 0.f};
#pragma unroll
    for (int i = 0; i < 2; ++i)
#pragma unroll
        for (int j = 0; j < 8; ++j) acc[i][j] = z;

    for (int kt = 0; kt < 4; ++kt) {
        // ---- X stage: fp32 -> bf16 fragment chunks ----
#pragma unroll
        for (int it = 0; it < 2; ++it) {
            int s = tid + it * 256;              // [0,512)
            int fp = s >> 6, ls = s & 63;
            int mf = fp & 3, ksl = fp >> 2;
            int row = m0 + mf * 16 + (ls & 15); if (row > NN - 1) row = NN - 1;
            const float* gp = Xp + (size_t)row * xPitch + kt * 64 + ksl * 32 + ((ls >> 4) << 3);
            float4 f0 = *(const float4*)gp, f1 = *(const float4*)(gp + 4);
            l64[s * 2]     = pack4(f0.x, f0.y, f0.z, f0.w);
            l64[s * 2 + 1] = pack4(f1.x, f1.y, f1.z, f1.w);
        }
        // ---- W stage: linear gload_lds of pre-permuted chunks ----
#pragma unroll
        for (int it = 0; it < 4; ++it) {
            int cb = (it * 4 + wid) * 64;        // [0,1024)
            gload16(wx + ((size_t)kt * 1024 + cb + lane) * 8,
                    (char*)lds + (512 + cb + lane) * 16);
            gload16(wn + ((size_t)kt * 1024 + cb + lane) * 8,
                    (char*)lds + (1536 + cb + lane) * 16);
        }
        __syncthreads();
        // ---- compute ----
        const int wB = wave_n ? 1536 : 512;
#pragma unroll
        for (int ksl = 0; ksl < 2; ++ksl) {
            bhalf8 a0 = lds[(ksl * 4 + wave_m * 2 + 0) * 64 + lane];
            bhalf8 a1 = lds[(ksl * 4 + wave_m * 2 + 1) * 64 + lane];
#pragma unroll
            for (int nf = 0; nf < 8; ++nf) {
                bhalf8 b = lds[wB + (ksl * 8 + nf) * 64 + lane];
                acc[0][nf] = __builtin_amdgcn_mfma_f32_16x16x32_bf16(a0, b, acc[0][nf], 0, 0, 0);
                acc[1][nf] = __builtin_amdgcn_mfma_f32_16x16x32_bf16(a1, b, acc[1][nf], 0, 0, 0);
            }
        }
        __syncthreads();
    }
    // ---- epilogue: D map col=lane&15, row=(lane>>4)*4+reg; all nt stores ----
    const int cl = lane & 15, rg = lane >> 4;
#pragma unroll
    for (int mf2 = 0; mf2 < 2; ++mf2) {
        int rowb = m0 + (wave_m * 2 + mf2) * 16 + rg * 4;
#pragma unroll
        for (int nf = 0; nf < 8; ++nf) {
            int cpr = nf * 16 + cl;              // [0,128)
            int icol = (cpr >> 6) * 128 + (cpr & 63);
            facc4 v = acc[mf2][nf];
#pragma unroll
            for (int rr = 0; rr < 4; ++rr) {
                int row = rowb + rr;
                if (row < NN) {
                    if (wave_n == 0) {
                        float f = fmaxf(v[rr], 0.0f);
                        __builtin_nontemporal_store(f, &outp[(size_t)row * 512 + obase + icol]);
                    } else {
                        __builtin_nontemporal_store(f2b(v[rr]),
                            &Pp[(size_t)(cpr >> 5) * (NN * 32) + (size_t)row * 32 + (cpr & 31)]);
                    }
                }
            }
        }
    }
}

// ---------------------------------------------------------------------------
// XCD-pinned sliced gather + mean + relu. 1D grid = GB * nPairs;
// pair = blockIdx.x & (nPairs-1) -> (slice, mp). With round-robin block->XCD
// placement each XCD owns one NN*64B = 3.2MB sub-table (L2-resident; nt
// writes don't evict it). Block = 64 nodes x 4 chunk-lanes.
// ---------------------------------------------------------------------------
__global__ __launch_bounds__(256)
void gatherS(const ushort_t* __restrict__ P, size_t PMpStr,
             const int* __restrict__ nb, size_t nMpStr,
             float* __restrict__ out, size_t oMpStr,
             int obase, int shift)
{
    const int b = blockIdx.x;
    const int pair = b & ((1 << shift) - 1);
    const int slice = pair & 3, mp = pair >> 2;
    const int nodeBase = (b >> shift) * 64;

    const ushort_t* Pp = P + (size_t)mp * PMpStr + (size_t)slice * (NN * 32);
    const int* nbp = nb + (size_t)mp * nMpStr;
    float* outp = out + (size_t)mp * oMpStr;

    __shared__ int nls[1024];
    {
        int i4 = nodeBase * 4 + threadIdx.x;     // int4 index into neigh
        int mx = NN * 4 - 1;
        if (i4 > mx) i4 = mx;
        ((int4*)nls)[threadIdx.x] = ((const int4*)nbp)[i4];
    }
    __syncthreads();

    const int nl = threadIdx.x >> 2, q = threadIdx.x & 3;
    const int node = nodeBase + nl;
    if (node >= NN) return;
    const int* nr = nls + nl * SNEI;
    float a0=0.f,a1=0.f,a2=0.f,a3=0.f,a4=0.f,a5=0.f,a6=0.f,a7=0.f;
#pragma unroll
    for (int s = 0; s < SNEI; ++s) {
        uint4 v = *(const uint4*)(Pp + (size_t)nr[s] * 32 + q * 8);
        a0 += b2f(v.x & 0xFFFFu); a1 += b2f(v.x >> 16);
        a2 += b2f(v.y & 0xFFFFu); a3 += b2f(v.y >> 16);
        a4 += b2f(v.z & 0xFFFFu); a5 += b2f(v.z >> 16);
        a6 += b2f(v.w & 0xFFFFu); a7 += b2f(v.w >> 16);
    }
    const float M = 0.0625f;
    f32x4 r0 = { fmaxf(a0*M, 0.f), fmaxf(a1*M, 0.f), fmaxf(a2*M, 0.f), fmaxf(a3*M, 0.f) };
    f32x4 r1 = { fmaxf(a4*M, 0.f), fmaxf(a5*M, 0.f), fmaxf(a6*M, 0.f), fmaxf(a7*M, 0.f) };
    const int coff = (slice >> 1) * 128 + 64 + (slice & 1) * 32 + q * 8;
    float* o = outp + (size_t)node * 512 + obase + coff;
    __builtin_nontemporal_store(r0, (f32x4*)o);
    __builtin_nontemporal_store(r1, (f32x4*)(o + 4));
}

// ---------------------------------------------------------------------------
extern "C" void kernel_launch(void* const* d_in, const int* in_sizes, int n_in,
                              void* d_out, int out_size, void* d_ws, size_t ws_size,
                              hipStream_t stream)
{
    const float* feats  = (const float*)d_in[0];
    const float* prepWp = (const float*)d_in[1];
    const float* Wx1    = (const float*)d_in[2];
    const float* Wn1    = (const float*)d_in[3];
    const float* Wx2    = (const float*)d_in[4];
    const float* Wn2    = (const float*)d_in[5];
    const int*   neigh  = (const int*)d_in[6];
    float* out = (float*)d_out;
    ushort_t* ws = (ushort_t*)d_ws;

    const size_t permElems = 262144;                       // 512 KB
    const size_t needBatched = (permElems + 2 * (size_t)NN * 128) * 2;  // ~26.1 MB
    const bool batched = ws_size >= needBatched;
    const int nmp = batched ? 2 : 1;

    ushort_t* perm = ws;
    ushort_t* P    = ws + permElems;                        // nmp * NN*128 bf16

    permSetup<<<1024, 256, 0, stream>>>(prepWp, Wx1, Wn1, Wx2, Wn2, perm);

    const size_t PStr = batched ? (size_t)NN * 128 : 0;
    const size_t oStr = batched ? (size_t)NN * 512 : 0;
    const size_t nStr = batched ? (size_t)NN * SNEI : 0;
    const size_t wStr = batched ? (size_t)8192 * 8 : 0;
    const int shift = batched ? 3 : 2;                     // pairs = 8 or 4
    const int passes = batched ? 1 : 2;

    for (int p = 0; p < passes; ++p) {
        const ushort_t* w1 = perm + (size_t)p * 8192 * 8;
        const ushort_t* w2 = perm + (size_t)(16384 + p * 8192) * 8;
        float* outp = out + (size_t)p * NN * 512;
        const int* nbp = neigh + (size_t)p * NN * SNEI;
        dim3 gp(GB, nmp);
        const int gg = GB << shift;

        // layer 1: X = feats (fp32, pitch 256, shared across mps)
        proj_gemm<<<gp, 256, 0, stream>>>(feats, 256, 0,
                                          w1, wStr, outp, oStr, 0, P, PStr);
        gatherS<<<gg, 256, 0, stream>>>(P, PStr, nbp, nStr, outp, oStr, 0, shift);

        // layer 2: X = out[:, 0:256] (fp32, pitch 512, just-written -> L3)
        proj_gemm<<<gp, 256, 0, stream>>>(outp, 512, oStr,
                                          w2, wStr, outp, oStr, 256, P, PStr);
        gatherS<<<gg, 256, 0, stream>>>(P, PStr, nbp, nStr, outp, oStr, 256, shift);
    }
}

// Round 8
// 184.456 us; speedup vs baseline: 1.1029x; 1.1029x over previous
//
#include <hip/hip_runtime.h>

#define NN 50000
#define SNEI 16
#define GB 782            // ceil(50000/64)

typedef unsigned short ushort_t;
typedef unsigned int uint_t;
typedef unsigned long long u64;
typedef __attribute__((ext_vector_type(8))) short bhalf8;
typedef __attribute__((ext_vector_type(4))) float facc4;
typedef __attribute__((ext_vector_type(4))) float f32x4;
typedef __attribute__((ext_vector_type(4))) int i32x4;
typedef __attribute__((ext_vector_type(4))) uint_t u32x4;

__device__ __forceinline__ float b2f(uint_t u) {
    union { uint_t u; float f; } x; x.u = u << 16; return x.f;
}
__device__ __forceinline__ ushort_t f2b(float f) {
    union { float f; uint_t u; } x; x.f = f;
    return (ushort_t)((x.u + 0x7FFFu + ((x.u >> 16) & 1u)) >> 16);
}
__device__ __forceinline__ u64 pack4(float a, float b, float c, float d) {
    return (u64)f2b(a) | ((u64)f2b(b) << 16) | ((u64)f2b(c) << 32) | ((u64)f2b(d) << 48);
}

typedef const __attribute__((address_space(1))) void cglb_t;
typedef __attribute__((address_space(3))) void lds3_t;
__device__ __forceinline__ void gload16(const void* g, void* l) {
    __builtin_amdgcn_global_load_lds((cglb_t*)g, (lds3_t*)l, 16, 0, 0);
}

// ---------------------------------------------------------------------------
// One-time weight setup (layout unchanged since round 5).
// Fragment k-bijection: chunk (ks*8+nf)*64+lane; elem j of lane l holds
// W[k][c], k = ks*32 + (l>>4)*8 + j (16B-contig), c = nf*16 + (l&15).
// Layer-1 weights pre-multiplied by prepW: W'1 = prepW @ W1  [256,128].
// perm chunks: [L1: mp0{x|n} mp1{x|n}][L2: same] = 32768 chunks.
// ---------------------------------------------------------------------------
__global__ void permSetup(const float* __restrict__ prepW,
                          const float* __restrict__ Wx1, const float* __restrict__ Wn1,
                          const float* __restrict__ Wx2, const float* __restrict__ Wn2,
                          ushort_t* __restrict__ dst)
{
    int e = blockIdx.x * 256 + threadIdx.x;
    int q8 = e >> 3, j = e & 7;
    int layer = q8 >> 14;
    int qq = q8 & 16383;
    int mp = qq >> 13, isN = (qq >> 12) & 1, q = qq & 4095;
    int lane = q & 63, nf = (q >> 6) & 7, ks = q >> 9;
    int c = nf * 16 + (lane & 15);                 // [0,128)
    int k = ks * 32 + ((lane >> 4) << 3) + j;      // [0,256)
    float v;
    if (layer == 0) {
        const float* W1 = (isN ? Wn1 : Wx1) + mp * 16384 + (c >> 6) * 8192 + (c & 63);
        const float* pw = prepW + (size_t)k * 128;
        float s0 = 0.f, s1 = 0.f;
#pragma unroll 4
        for (int p = 0; p < 128; p += 2) {
            s0 += pw[p]     * W1[(size_t)p * 64];
            s1 += pw[p + 1] * W1[(size_t)(p + 1) * 64];
        }
        v = s0 + s1;
    } else {
        const float* W2 = (isN ? Wn2 : Wx2) + mp * 32768 + (c >> 6) * 16384 + (size_t)k * 64 + (c & 63);
        v = *W2;
    }
    dst[(size_t)q8 * 8 + j] = f2b(v);
}

// ---------------------------------------------------------------------------
// Dual-projection GEMM, K=256, X fp32 (feats pitch 256, or out pitch 512).
// wave_n=0: relu(X@Wx) -> NT fp32 out x-slots at obase (bypass L2; L3 serves
//           any re-read).  wave_n=1: X@Wn -> CACHED bf16 P, sliced layout
//           P[slice][node][32] (read by next gather -> must cache).
// NTX: nt-load the X operand (layer 2: read-once from L3, don't pollute L2).
// Tile 64 rows x 128 cols/role, BK=64, 4 waves, 40KB LDS, 4 blocks/CU.
// LDS chunks: X [0,512) | Wx [512,1536) | Wn [1536,2560).
// ---------------------------------------------------------------------------
template<bool NTX>
__global__ __launch_bounds__(256, 4)
void proj_gemm(const float* __restrict__ X, int xPitch, size_t xMpStr,
               const ushort_t* __restrict__ W, size_t wMpStr,
               float* __restrict__ out, size_t oMpStr, int obase,
               ushort_t* __restrict__ P, size_t PMpStr)
{
    __shared__ bhalf8 lds[2560];
    u64* l64 = (u64*)lds;
    const int tid = threadIdx.x;
    const int lane = tid & 63;
    const int wid = tid >> 6;
    const int wave_m = wid >> 1, wave_n = wid & 1;
    const int m0 = blockIdx.x * 64;
    const int mp = blockIdx.y;

    const float* Xp = X + (size_t)mp * xMpStr;
    const ushort_t* wx = W + (size_t)mp * wMpStr;
    const ushort_t* wn = wx + 4096 * 8;
    float* outp = out + (size_t)mp * oMpStr;
    ushort_t* Pp = P + (size_t)mp * PMpStr;

    facc4 acc[2][8];
    const facc4 z = {0.f, 0.f, 0.f, 0.f};
#pragma unroll
    for (int i = 0; i < 2; ++i)
#pragma unroll
        for (int j = 0; j < 8; ++j) acc[i][j] = z;

    for (int kt = 0; kt < 4; ++kt) {
        // ---- X stage: fp32 -> bf16 fragment chunks ----
#pragma unroll
        for (int it = 0; it < 2; ++it) {
            int s = tid + it * 256;              // [0,512)
            int fp = s >> 6, ls = s & 63;
            int mf = fp & 3, ksl = fp >> 2;
            int row = m0 + mf * 16 + (ls & 15); if (row > NN - 1) row = NN - 1;
            const f32x4* gp = (const f32x4*)(Xp + (size_t)row * xPitch + kt * 64 + ksl * 32 + ((ls >> 4) << 3));
            f32x4 f0, f1;
            if constexpr (NTX) { f0 = __builtin_nontemporal_load(gp); f1 = __builtin_nontemporal_load(gp + 1); }
            else               { f0 = gp[0]; f1 = gp[1]; }
            l64[s * 2]     = pack4(f0[0], f0[1], f0[2], f0[3]);
            l64[s * 2 + 1] = pack4(f1[0], f1[1], f1[2], f1[3]);
        }
        // ---- W stage: linear gload_lds of pre-permuted chunks (cached) ----
#pragma unroll
        for (int it = 0; it < 4; ++it) {
            int cb = (it * 4 + wid) * 64;        // [0,1024)
            gload16(wx + ((size_t)kt * 1024 + cb + lane) * 8,
                    (char*)lds + (512 + cb + lane) * 16);
            gload16(wn + ((size_t)kt * 1024 + cb + lane) * 8,
                    (char*)lds + (1536 + cb + lane) * 16);
        }
        __syncthreads();
        // ---- compute ----
        const int wB = wave_n ? 1536 : 512;
#pragma unroll
        for (int ksl = 0; ksl < 2; ++ksl) {
            bhalf8 a0 = lds[(ksl * 4 + wave_m * 2 + 0) * 64 + lane];
            bhalf8 a1 = lds[(ksl * 4 + wave_m * 2 + 1) * 64 + lane];
#pragma unroll
            for (int nf = 0; nf < 8; ++nf) {
                bhalf8 b = lds[wB + (ksl * 8 + nf) * 64 + lane];
                acc[0][nf] = __builtin_amdgcn_mfma_f32_16x16x32_bf16(a0, b, acc[0][nf], 0, 0, 0);
                acc[1][nf] = __builtin_amdgcn_mfma_f32_16x16x32_bf16(a1, b, acc[1][nf], 0, 0, 0);
            }
        }
        __syncthreads();
    }
    // ---- epilogue: D map col=lane&15, row=(lane>>4)*4+reg ----
    const int cl = lane & 15, rg = lane >> 4;
#pragma unroll
    for (int mf2 = 0; mf2 < 2; ++mf2) {
        int rowb = m0 + (wave_m * 2 + mf2) * 16 + rg * 4;
#pragma unroll
        for (int nf = 0; nf < 8; ++nf) {
            int cpr = nf * 16 + cl;              // [0,128)
            int icol = (cpr >> 6) * 128 + (cpr & 63);
            facc4 v = acc[mf2][nf];
#pragma unroll
            for (int rr = 0; rr < 4; ++rr) {
                int row = rowb + rr;
                if (row < NN) {
                    if (wave_n == 0) {
                        float f = fmaxf(v[rr], 0.0f);
                        __builtin_nontemporal_store(f, &outp[(size_t)row * 512 + obase + icol]);
                    } else {
                        // CACHED store: P is the next gather's hot read set
                        Pp[(size_t)(cpr >> 5) * (NN * 32) + (size_t)row * 32 + (cpr & 31)] = f2b(v[rr]);
                    }
                }
            }
        }
    }
}

// ---------------------------------------------------------------------------
// XCD-pinned sliced gather + mean + relu. 1D grid = GB * nPairs;
// pair = blockIdx.x & (nPairs-1) -> (slice, mp); round-robin block->XCD gives
// each XCD one NN*64B = 3.2MB sub-table. nt-load neigh + nt-store output so
// NOTHING evicts the sub-table from the pinned L2. P reads are cached.
// Block = 64 nodes x 4 chunk-lanes.
// ---------------------------------------------------------------------------
__global__ __launch_bounds__(256)
void gatherS(const ushort_t* __restrict__ P, size_t PMpStr,
             const int* __restrict__ nb, size_t nMpStr,
             float* __restrict__ out, size_t oMpStr,
             int obase, int shift)
{
    const int b = blockIdx.x;
    const int pair = b & ((1 << shift) - 1);
    const int slice = pair & 3, mp = pair >> 2;
    const int nodeBase = (b >> shift) * 64;

    const ushort_t* Pp = P + (size_t)mp * PMpStr + (size_t)slice * (NN * 32);
    const int* nbp = nb + (size_t)mp * nMpStr;
    float* outp = out + (size_t)mp * oMpStr;

    __shared__ int nls[1024];
    {
        int i4 = nodeBase * 4 + threadIdx.x;     // int4 index into neigh
        int mx = NN * 4 - 1;
        if (i4 > mx) i4 = mx;
        i32x4 v = __builtin_nontemporal_load((const i32x4*)nbp + i4);
        ((i32x4*)nls)[threadIdx.x] = v;
    }
    __syncthreads();

    const int nl = threadIdx.x >> 2, q = threadIdx.x & 3;
    const int node = nodeBase + nl;
    if (node >= NN) return;
    const int* nr = nls + nl * SNEI;
    float a0=0.f,a1=0.f,a2=0.f,a3=0.f,a4=0.f,a5=0.f,a6=0.f,a7=0.f;
#pragma unroll
    for (int s = 0; s < SNEI; ++s) {
        u32x4 v = *(const u32x4*)(Pp + (size_t)nr[s] * 32 + q * 8);   // cached
        a0 += b2f(v.x & 0xFFFFu); a1 += b2f(v.x >> 16);
        a2 += b2f(v.y & 0xFFFFu); a3 += b2f(v.y >> 16);
        a4 += b2f(v.z & 0xFFFFu); a5 += b2f(v.z >> 16);
        a6 += b2f(v.w & 0xFFFFu); a7 += b2f(v.w >> 16);
    }
    const float M = 0.0625f;
    f32x4 r0 = { fmaxf(a0*M, 0.f), fmaxf(a1*M, 0.f), fmaxf(a2*M, 0.f), fmaxf(a3*M, 0.f) };
    f32x4 r1 = { fmaxf(a4*M, 0.f), fmaxf(a5*M, 0.f), fmaxf(a6*M, 0.f), fmaxf(a7*M, 0.f) };
    const int coff = (slice >> 1) * 128 + 64 + (slice & 1) * 32 + q * 8;
    float* o = outp + (size_t)node * 512 + obase + coff;
    __builtin_nontemporal_store(r0, (f32x4*)o);
    __builtin_nontemporal_store(r1, (f32x4*)(o + 4));
}

// ---------------------------------------------------------------------------
extern "C" void kernel_launch(void* const* d_in, const int* in_sizes, int n_in,
                              void* d_out, int out_size, void* d_ws, size_t ws_size,
                              hipStream_t stream)
{
    const float* feats  = (const float*)d_in[0];
    const float* prepWp = (const float*)d_in[1];
    const float* Wx1    = (const float*)d_in[2];
    const float* Wn1    = (const float*)d_in[3];
    const float* Wx2    = (const float*)d_in[4];
    const float* Wn2    = (const float*)d_in[5];
    const int*   neigh  = (const int*)d_in[6];
    float* out = (float*)d_out;
    ushort_t* ws = (ushort_t*)d_ws;

    const size_t permElems = 262144;                       // 512 KB
    const size_t needBatched = (permElems + 2 * (size_t)NN * 128) * 2;  // ~26.1 MB
    const bool batched = ws_size >= needBatched;
    const int nmp = batched ? 2 : 1;

    ushort_t* perm = ws;
    ushort_t* P    = ws + permElems;                        // nmp * NN*128 bf16

    permSetup<<<1024, 256, 0, stream>>>(prepWp, Wx1, Wn1, Wx2, Wn2, perm);

    const size_t PStr = batched ? (size_t)NN * 128 : 0;
    const size_t oStr = batched ? (size_t)NN * 512 : 0;
    const size_t nStr = batched ? (size_t)NN * SNEI : 0;
    const size_t wStr = batched ? (size_t)8192 * 8 : 0;
    const int shift = batched ? 3 : 2;                     // pairs = 8 or 4
    const int passes = batched ? 1 : 2;

    for (int p = 0; p < passes; ++p) {
        const ushort_t* w1 = perm + (size_t)p * 8192 * 8;
        const ushort_t* w2 = perm + (size_t)(16384 + p * 8192) * 8;
        float* outp = out + (size_t)p * NN * 512;
        const int* nbp = neigh + (size_t)p * NN * SNEI;
        dim3 gp(GB, nmp);
        const int gg = GB << shift;

        // layer 1: X = feats (fp32, pitch 256, shared across mps, cached)
        proj_gemm<false><<<gp, 256, 0, stream>>>(feats, 256, 0,
                                                 w1, wStr, outp, oStr, 0, P, PStr);
        gatherS<<<gg, 256, 0, stream>>>(P, PStr, nbp, nStr, outp, oStr, 0, shift);

        // layer 2: X = out[:, 0:256] (fp32, pitch 512, read-once -> nt-load)
        proj_gemm<true><<<gp, 256, 0, stream>>>(outp, 512, oStr,
                                                w2, wStr, outp, oStr, 256, P, PStr);
        gatherS<<<gg, 256, 0, stream>>>(P, PStr, nbp, nStr, outp, oStr, 256, shift);
    }
}

// Round 9
// 181.513 us; speedup vs baseline: 1.1207x; 1.0162x over previous
//
#include <hip/hip_runtime.h>

#define NN 50000
#define SNEI 16
#define GB 782            // ceil(50000/64)

typedef unsigned short ushort_t;
typedef unsigned int uint_t;
typedef unsigned long long u64;
typedef __attribute__((ext_vector_type(8))) short bhalf8;
typedef __attribute__((ext_vector_type(4))) float facc4;
typedef __attribute__((ext_vector_type(4))) float f32x4;
typedef __attribute__((ext_vector_type(4))) int i32x4;
typedef __attribute__((ext_vector_type(4))) uint_t u32x4;

__device__ __forceinline__ float b2f(uint_t u) {
    union { uint_t u; float f; } x; x.u = u << 16; return x.f;
}
__device__ __forceinline__ ushort_t f2b(float f) {
    union { float f; uint_t u; } x; x.f = f;
    return (ushort_t)((x.u + 0x7FFFu + ((x.u >> 16) & 1u)) >> 16);
}
__device__ __forceinline__ u64 pack4(float a, float b, float c, float d) {
    return (u64)f2b(a) | ((u64)f2b(b) << 16) | ((u64)f2b(c) << 32) | ((u64)f2b(d) << 48);
}

typedef const __attribute__((address_space(1))) void cglb_t;
typedef __attribute__((address_space(3))) void lds3_t;
__device__ __forceinline__ void gload16(const void* g, void* l) {
    __builtin_amdgcn_global_load_lds((cglb_t*)g, (lds3_t*)l, 16, 0, 0);
}

// ---------------------------------------------------------------------------
// One-time weight setup (layout unchanged since round 5).
// Fragment k-bijection: chunk (ks*8+nf)*64+lane; elem j of lane l holds
// W[k][c], k = ks*32 + (l>>4)*8 + j (16B-contig), c = nf*16 + (l&15).
// Layer-1 weights pre-multiplied by prepW: W'1 = prepW @ W1  [256,128].
// perm chunks: [L1: mp0{x|n} mp1{x|n}][L2: same] = 32768 chunks.
// ---------------------------------------------------------------------------
__global__ void permSetup(const float* __restrict__ prepW,
                          const float* __restrict__ Wx1, const float* __restrict__ Wn1,
                          const float* __restrict__ Wx2, const float* __restrict__ Wn2,
                          ushort_t* __restrict__ dst)
{
    int e = blockIdx.x * 256 + threadIdx.x;
    int q8 = e >> 3, j = e & 7;
    int layer = q8 >> 14;
    int qq = q8 & 16383;
    int mp = qq >> 13, isN = (qq >> 12) & 1, q = qq & 4095;
    int lane = q & 63, nf = (q >> 6) & 7, ks = q >> 9;
    int c = nf * 16 + (lane & 15);                 // [0,128)
    int k = ks * 32 + ((lane >> 4) << 3) + j;      // [0,256)
    float v;
    if (layer == 0) {
        const float* W1 = (isN ? Wn1 : Wx1) + mp * 16384 + (c >> 6) * 8192 + (c & 63);
        const float* pw = prepW + (size_t)k * 128;
        float s0 = 0.f, s1 = 0.f;
#pragma unroll 4
        for (int p = 0; p < 128; p += 2) {
            s0 += pw[p]     * W1[(size_t)p * 64];
            s1 += pw[p + 1] * W1[(size_t)(p + 1) * 64];
        }
        v = s0 + s1;
    } else {
        const float* W2 = (isN ? Wn2 : Wx2) + mp * 32768 + (c >> 6) * 16384 + (size_t)k * 64 + (c & 63);
        v = *W2;
    }
    dst[(size_t)q8 * 8 + j] = f2b(v);
}

// ---------------------------------------------------------------------------
// Dual-projection GEMM, K=256, X fp32 (feats pitch 256, or out pitch 512).
// wave_n=0: relu(X@Wx) -> LDS transpose -> fully line-coalesced NT fp32 out.
// wave_n=1: X@Wn -> CACHED bf16 P (L2-merged scatter), sliced P[slice][n][32].
// NTX: nt-load the X operand (layer 2: read-once from L3).
// Tile 64 rows x 128 cols/role, BK=64, 4 waves, 40KB LDS, 4 blocks/CU.
// LDS (main loop): X [0,512) | Wx [512,1536) | Wn [1536,2560) chunks.
// LDS (epilogue):  fp32 [64][132] overlay (33 KB).
// ---------------------------------------------------------------------------
template<bool NTX>
__global__ __launch_bounds__(256, 4)
void proj_gemm(const float* __restrict__ X, int xPitch, size_t xMpStr,
               const ushort_t* __restrict__ W, size_t wMpStr,
               float* __restrict__ out, size_t oMpStr, int obase,
               ushort_t* __restrict__ P, size_t PMpStr)
{
    __shared__ bhalf8 lds[2560];
    u64* l64 = (u64*)lds;
    const int tid = threadIdx.x;
    const int lane = tid & 63;
    const int wid = tid >> 6;
    const int wave_m = wid >> 1, wave_n = wid & 1;
    const int m0 = blockIdx.x * 64;
    const int mp = blockIdx.y;

    const float* Xp = X + (size_t)mp * xMpStr;
    const ushort_t* wx = W + (size_t)mp * wMpStr;
    const ushort_t* wn = wx + 4096 * 8;
    float* outp = out + (size_t)mp * oMpStr;
    ushort_t* Pp = P + (size_t)mp * PMpStr;

    facc4 acc[2][8];
    const facc4 z = {0.f, 0.f, 0.f, 0.f};
#pragma unroll
    for (int i = 0; i < 2; ++i)
#pragma unroll
        for (int j = 0; j < 8; ++j) acc[i][j] = z;

    for (int kt = 0; kt < 4; ++kt) {
        // ---- X stage: fp32 -> bf16 fragment chunks ----
#pragma unroll
        for (int it = 0; it < 2; ++it) {
            int s = tid + it * 256;              // [0,512)
            int fp = s >> 6, ls = s & 63;
            int mf = fp & 3, ksl = fp >> 2;
            int row = m0 + mf * 16 + (ls & 15); if (row > NN - 1) row = NN - 1;
            const f32x4* gp = (const f32x4*)(Xp + (size_t)row * xPitch + kt * 64 + ksl * 32 + ((ls >> 4) << 3));
            f32x4 f0, f1;
            if constexpr (NTX) { f0 = __builtin_nontemporal_load(gp); f1 = __builtin_nontemporal_load(gp + 1); }
            else               { f0 = gp[0]; f1 = gp[1]; }
            l64[s * 2]     = pack4(f0[0], f0[1], f0[2], f0[3]);
            l64[s * 2 + 1] = pack4(f1[0], f1[1], f1[2], f1[3]);
        }
        // ---- W stage: linear gload_lds of pre-permuted chunks (cached) ----
#pragma unroll
        for (int it = 0; it < 4; ++it) {
            int cb = (it * 4 + wid) * 64;        // [0,1024)
            gload16(wx + ((size_t)kt * 1024 + cb + lane) * 8,
                    (char*)lds + (512 + cb + lane) * 16);
            gload16(wn + ((size_t)kt * 1024 + cb + lane) * 8,
                    (char*)lds + (1536 + cb + lane) * 16);
        }
        __syncthreads();
        // ---- compute ----
        const int wB = wave_n ? 1536 : 512;
#pragma unroll
        for (int ksl = 0; ksl < 2; ++ksl) {
            bhalf8 a0 = lds[(ksl * 4 + wave_m * 2 + 0) * 64 + lane];
            bhalf8 a1 = lds[(ksl * 4 + wave_m * 2 + 1) * 64 + lane];
#pragma unroll
            for (int nf = 0; nf < 8; ++nf) {
                bhalf8 b = lds[wB + (ksl * 8 + nf) * 64 + lane];
                acc[0][nf] = __builtin_amdgcn_mfma_f32_16x16x32_bf16(a0, b, acc[0][nf], 0, 0, 0);
                acc[1][nf] = __builtin_amdgcn_mfma_f32_16x16x32_bf16(a1, b, acc[1][nf], 0, 0, 0);
            }
        }
        __syncthreads();
    }
    // ---- epilogue. D map: col=lane&15, row=(lane>>4)*4+reg ----
    const int cl = lane & 15, rg = lane >> 4;
    float* xl = (float*)lds;                      // [64][132] fp32 overlay
    if (wave_n == 0) {
        // x-waves: relu + deposit into LDS (2-way-free banks via pitch 132)
#pragma unroll
        for (int mf2 = 0; mf2 < 2; ++mf2) {
            int rowl = (wave_m * 2 + mf2) * 16 + rg * 4;
#pragma unroll
            for (int nf = 0; nf < 8; ++nf) {
                int cpr = nf * 16 + cl;
                facc4 v = acc[mf2][nf];
#pragma unroll
                for (int rr = 0; rr < 4; ++rr)
                    xl[(rowl + rr) * 132 + cpr] = fmaxf(v[rr], 0.0f);
            }
        }
    } else {
        // P-waves: cached scattered stores (L2 merges; read next dispatch)
#pragma unroll
        for (int mf2 = 0; mf2 < 2; ++mf2) {
            int rowb = m0 + (wave_m * 2 + mf2) * 16 + rg * 4;
#pragma unroll
            for (int nf = 0; nf < 8; ++nf) {
                int cpr = nf * 16 + cl;
                facc4 v = acc[mf2][nf];
#pragma unroll
                for (int rr = 0; rr < 4; ++rr) {
                    int row = rowb + rr;
                    if (row < NN)
                        Pp[(size_t)(cpr >> 5) * (NN * 32) + (size_t)row * 32 + (cpr & 31)] = f2b(v[rr]);
                }
            }
        }
    }
    __syncthreads();
    // all waves: line-coalesced nt stores (per inst: 4 rows x 256B contig)
    {
#pragma unroll
        for (int j = 0; j < 4; ++j) {
            int rowl = wid * 16 + j * 4 + rg / 1;   // rg in [0,4): 4 rows/inst
            int rowl2 = wid * 16 + j * 4 + (lane >> 4);
            int row = m0 + rowl2;
            (void)rowl;
#pragma unroll
            for (int c = 0; c < 2; ++c) {
                int base = rowl2 * 132 + c * 64 + cl * 4;
                f32x4 v = *(f32x4*)&xl[base];
                if (row < NN)
                    __builtin_nontemporal_store(v,
                        (f32x4*)&outp[(size_t)row * 512 + obase + c * 128 + cl * 4]);
            }
        }
    }
}

// ---------------------------------------------------------------------------
// XCD-pinned sliced gather + mean + relu. 1D grid = GB * nPairs;
// pair = blockIdx.x & (nPairs-1) -> (slice, mp); round-robin block->XCD gives
// each XCD one NN*64B = 3.2MB sub-table. nt-load neigh; P reads cached;
// output staged through LDS -> full-128B-line nt stores (8 lanes x 16B/row).
// Block = 64 nodes x 4 chunk-lanes.
// ---------------------------------------------------------------------------
__global__ __launch_bounds__(256)
void gatherS(const ushort_t* __restrict__ P, size_t PMpStr,
             const int* __restrict__ nb, size_t nMpStr,
             float* __restrict__ out, size_t oMpStr,
             int obase, int shift)
{
    const int b = blockIdx.x;
    const int pair = b & ((1 << shift) - 1);
    const int slice = pair & 3, mp = pair >> 2;
    const int nodeBase = (b >> shift) * 64;

    const ushort_t* Pp = P + (size_t)mp * PMpStr + (size_t)slice * (NN * 32);
    const int* nbp = nb + (size_t)mp * nMpStr;
    float* outp = out + (size_t)mp * oMpStr;

    __shared__ int nls[1024];
    __shared__ float og[64 * 36];                 // 9 KB staging, pitch 36
    {
        int i4 = nodeBase * 4 + threadIdx.x;     // int4 index into neigh
        int mx = NN * 4 - 1;
        if (i4 > mx) i4 = mx;
        i32x4 v = __builtin_nontemporal_load((const i32x4*)nbp + i4);
        ((i32x4*)nls)[threadIdx.x] = v;
    }
    __syncthreads();

    const int nl = threadIdx.x >> 2, q = threadIdx.x & 3;
    const int* nr = nls + nl * SNEI;
    float a0=0.f,a1=0.f,a2=0.f,a3=0.f,a4=0.f,a5=0.f,a6=0.f,a7=0.f;
#pragma unroll
    for (int s = 0; s < SNEI; ++s) {
        u32x4 v = *(const u32x4*)(Pp + (size_t)nr[s] * 32 + q * 8);   // cached
        a0 += b2f(v.x & 0xFFFFu); a1 += b2f(v.x >> 16);
        a2 += b2f(v.y & 0xFFFFu); a3 += b2f(v.y >> 16);
        a4 += b2f(v.z & 0xFFFFu); a5 += b2f(v.z >> 16);
        a6 += b2f(v.w & 0xFFFFu); a7 += b2f(v.w >> 16);
    }
    const float M = 0.0625f;
    f32x4 r0 = { fmaxf(a0*M, 0.f), fmaxf(a1*M, 0.f), fmaxf(a2*M, 0.f), fmaxf(a3*M, 0.f) };
    f32x4 r1 = { fmaxf(a4*M, 0.f), fmaxf(a5*M, 0.f), fmaxf(a6*M, 0.f), fmaxf(a7*M, 0.f) };
    *(f32x4*)&og[nl * 36 + q * 8]     = r0;
    *(f32x4*)&og[nl * 36 + q * 8 + 4] = r1;
    __syncthreads();

    // line-coalesced store: per inst 8 rows x 128B full lines
    const int coff0 = (slice >> 1) * 128 + 64 + (slice & 1) * 32;
#pragma unroll
    for (int it = 0; it < 2; ++it) {
        int rl = it * 32 + (threadIdx.x >> 3), sub = threadIdx.x & 7;
        int node = nodeBase + rl;
        f32x4 v = *(f32x4*)&og[rl * 36 + sub * 4];
        if (node < NN)
            __builtin_nontemporal_store(v,
                (f32x4*)(outp + (size_t)node * 512 + obase + coff0 + sub * 4));
    }
}

// ---------------------------------------------------------------------------
extern "C" void kernel_launch(void* const* d_in, const int* in_sizes, int n_in,
                              void* d_out, int out_size, void* d_ws, size_t ws_size,
                              hipStream_t stream)
{
    const float* feats  = (const float*)d_in[0];
    const float* prepWp = (const float*)d_in[1];
    const float* Wx1    = (const float*)d_in[2];
    const float* Wn1    = (const float*)d_in[3];
    const float* Wx2    = (const float*)d_in[4];
    const float* Wn2    = (const float*)d_in[5];
    const int*   neigh  = (const int*)d_in[6];
    float* out = (float*)d_out;
    ushort_t* ws = (ushort_t*)d_ws;

    const size_t permElems = 262144;                       // 512 KB
    const size_t needBatched = (permElems + 2 * (size_t)NN * 128) * 2;  // ~26.1 MB
    const bool batched = ws_size >= needBatched;
    const int nmp = batched ? 2 : 1;

    ushort_t* perm = ws;
    ushort_t* P    = ws + permElems;                        // nmp * NN*128 bf16

    permSetup<<<1024, 256, 0, stream>>>(prepWp, Wx1, Wn1, Wx2, Wn2, perm);

    const size_t PStr = batched ? (size_t)NN * 128 : 0;
    const size_t oStr = batched ? (size_t)NN * 512 : 0;
    const size_t nStr = batched ? (size_t)NN * SNEI : 0;
    const size_t wStr = batched ? (size_t)8192 * 8 : 0;
    const int shift = batched ? 3 : 2;                     // pairs = 8 or 4
    const int passes = batched ? 1 : 2;

    for (int p = 0; p < passes; ++p) {
        const ushort_t* w1 = perm + (size_t)p * 8192 * 8;
        const ushort_t* w2 = perm + (size_t)(16384 + p * 8192) * 8;
        float* outp = out + (size_t)p * NN * 512;
        const int* nbp = neigh + (size_t)p * NN * SNEI;
        dim3 gp(GB, nmp);
        const int gg = GB << shift;

        // layer 1: X = feats (fp32, pitch 256, shared across mps, cached)
        proj_gemm<false><<<gp, 256, 0, stream>>>(feats, 256, 0,
                                                 w1, wStr, outp, oStr, 0, P, PStr);
        gatherS<<<gg, 256, 0, stream>>>(P, PStr, nbp, nStr, outp, oStr, 0, shift);

        // layer 2: X = out[:, 0:256] (fp32, pitch 512, read-once -> nt-load)
        proj_gemm<true><<<gp, 256, 0, stream>>>(outp, 512, oStr,
                                                w2, wStr, outp, oStr, 256, P, PStr);
        gatherS<<<gg, 256, 0, stream>>>(P, PStr, nbp, nStr, outp, oStr, 256, shift);
    }
}

// Round 10
// 173.676 us; speedup vs baseline: 1.1713x; 1.0451x over previous
//
#include <hip/hip_runtime.h>

#define NN 50000
#define SNEI 16
#define GB 782            // ceil(50000/64)

typedef unsigned short ushort_t;
typedef unsigned int uint_t;
typedef unsigned long long u64;
typedef __attribute__((ext_vector_type(8))) short bhalf8;
typedef __attribute__((ext_vector_type(4))) float facc4;
typedef __attribute__((ext_vector_type(4))) float f32x4;
typedef __attribute__((ext_vector_type(4))) int i32x4;
typedef __attribute__((ext_vector_type(4))) uint_t u32x4;

__device__ __forceinline__ float b2f(uint_t u) {
    union { uint_t u; float f; } x; x.u = u << 16; return x.f;
}
__device__ __forceinline__ ushort_t f2b(float f) {
    union { float f; uint_t u; } x; x.f = f;
    return (ushort_t)((x.u + 0x7FFFu + ((x.u >> 16) & 1u)) >> 16);
}
__device__ __forceinline__ u64 pack4(float a, float b, float c, float d) {
    return (u64)f2b(a) | ((u64)f2b(b) << 16) | ((u64)f2b(c) << 32) | ((u64)f2b(d) << 48);
}

typedef const __attribute__((address_space(1))) void cglb_t;
typedef __attribute__((address_space(3))) void lds3_t;
__device__ __forceinline__ void gload16(const void* g, void* l) {
    __builtin_amdgcn_global_load_lds((cglb_t*)g, (lds3_t*)l, 16, 0, 0);
}

// ---------------------------------------------------------------------------
// One-time weight setup (layout unchanged since round 5).
// Fragment k-bijection: chunk (ks*8+nf)*64+lane; elem j of lane l holds
// W[k][c], k = ks*32 + (l>>4)*8 + j (16B-contig), c = nf*16 + (l&15).
// Layer-1 weights pre-multiplied by prepW: W'1 = prepW @ W1  [256,128].
// perm chunks: [L1: mp0{x|n} mp1{x|n}][L2: same] = 32768 chunks.
// ---------------------------------------------------------------------------
__global__ void permSetup(const float* __restrict__ prepW,
                          const float* __restrict__ Wx1, const float* __restrict__ Wn1,
                          const float* __restrict__ Wx2, const float* __restrict__ Wn2,
                          ushort_t* __restrict__ dst)
{
    int e = blockIdx.x * 256 + threadIdx.x;
    int q8 = e >> 3, j = e & 7;
    int layer = q8 >> 14;
    int qq = q8 & 16383;
    int mp = qq >> 13, isN = (qq >> 12) & 1, q = qq & 4095;
    int lane = q & 63, nf = (q >> 6) & 7, ks = q >> 9;
    int c = nf * 16 + (lane & 15);                 // [0,128)
    int k = ks * 32 + ((lane >> 4) << 3) + j;      // [0,256)
    float v;
    if (layer == 0) {
        const float* W1 = (isN ? Wn1 : Wx1) + mp * 16384 + (c >> 6) * 8192 + (c & 63);
        const float* pw = prepW + (size_t)k * 128;
        float s0 = 0.f, s1 = 0.f;
#pragma unroll 4
        for (int p = 0; p < 128; p += 2) {
            s0 += pw[p]     * W1[(size_t)p * 64];
            s1 += pw[p + 1] * W1[(size_t)(p + 1) * 64];
        }
        v = s0 + s1;
    } else {
        const float* W2 = (isN ? Wn2 : Wx2) + mp * 32768 + (c >> 6) * 16384 + (size_t)k * 64 + (c & 63);
        v = *W2;
    }
    dst[(size_t)q8 * 8 + j] = f2b(v);
}

// ---------------------------------------------------------------------------
// Layer-1 projection, BOTH metapaths fused: X (feats) staged ONCE per tile;
// 8 waves = 2 wave_m x 4 roles (mp,isN). isN=0: relu(X@Wx) -> LDS overlay ->
// coalesced nt fp32 out + cached bf16 h1x. isN=1: X@Wn -> cached bf16 P
// (sliced P[slice][node][32]).
// LDS: X [0,512) | W[role] [512+role*1024, ...) chunks = 72KB; overlay
// 2 x [64][132] fp32 (66KB) reuses the same LDS after the K-loop.
// ---------------------------------------------------------------------------
__global__ __launch_bounds__(512, 4)
void proj1_gemm(const float* __restrict__ X,
                const ushort_t* __restrict__ W, size_t wMpStr,
                float* __restrict__ out, size_t oMpStr,
                ushort_t* __restrict__ h1, size_t hMpStr,
                ushort_t* __restrict__ P, size_t PMpStr)
{
    __shared__ bhalf8 lds[4608];                  // 72KB
    u64* l64 = (u64*)lds;
    const int tid = threadIdx.x;
    const int lane = tid & 63;
    const int wid = tid >> 6;                     // 0..7
    const int wave_m = wid >> 2;                  // 0,1
    const int role = wid & 3;                     // (mp<<1)|isN
    const int mp = role >> 1, isN = role & 1;
    const int m0 = blockIdx.x * 64;

    facc4 acc[2][8];
    const facc4 z = {0.f, 0.f, 0.f, 0.f};
#pragma unroll
    for (int i = 0; i < 2; ++i)
#pragma unroll
        for (int j = 0; j < 8; ++j) acc[i][j] = z;

    for (int kt = 0; kt < 4; ++kt) {
        // ---- X stage (once, shared by all 4 roles): 512 chunks ----
        {
            int s = tid;
            int fp = s >> 6, ls = s & 63;
            int mf = fp & 3, ksl = fp >> 2;
            int row = m0 + mf * 16 + (ls & 15); if (row > NN - 1) row = NN - 1;
            const f32x4* gp = (const f32x4*)(X + (size_t)row * 256 + kt * 64 + ksl * 32 + ((ls >> 4) << 3));
            f32x4 f0 = gp[0], f1 = gp[1];
            l64[s * 2]     = pack4(f0[0], f0[1], f0[2], f0[3]);
            l64[s * 2 + 1] = pack4(f1[0], f1[1], f1[2], f1[3]);
        }
        // ---- W stage: 4096 chunks (4 matrices), linear gload_lds ----
#pragma unroll
        for (int it = 0; it < 8; ++it) {
            int c4 = it * 512 + tid;             // [0,4096)
            int m = c4 >> 10, c = c4 & 1023;
            const ushort_t* src = W + (size_t)(m >> 1) * wMpStr + (m & 1) * 32768
                                + ((size_t)kt * 1024 + c) * 8;
            gload16(src, (char*)lds + (512 + m * 1024 + c) * 16);
        }
        __syncthreads();
        // ---- compute: each wave its (mp,isN) matrix ----
        const int wB = 512 + role * 1024;
#pragma unroll
        for (int ksl = 0; ksl < 2; ++ksl) {
            bhalf8 a0 = lds[(ksl * 4 + wave_m * 2 + 0) * 64 + lane];
            bhalf8 a1 = lds[(ksl * 4 + wave_m * 2 + 1) * 64 + lane];
#pragma unroll
            for (int nf = 0; nf < 8; ++nf) {
                bhalf8 b = lds[wB + (ksl * 8 + nf) * 64 + lane];
                acc[0][nf] = __builtin_amdgcn_mfma_f32_16x16x32_bf16(a0, b, acc[0][nf], 0, 0, 0);
                acc[1][nf] = __builtin_amdgcn_mfma_f32_16x16x32_bf16(a1, b, acc[1][nf], 0, 0, 0);
            }
        }
        __syncthreads();
    }
    // ---- epilogue. D map: col=lane&15, row=(lane>>4)*4+reg ----
    const int cl = lane & 15, rg = lane >> 4;
    if (isN == 0) {
        float* xl = (float*)lds + mp * (64 * 132);
#pragma unroll
        for (int mf2 = 0; mf2 < 2; ++mf2) {
            int rowl = (wave_m * 2 + mf2) * 16 + rg * 4;
#pragma unroll
            for (int nf = 0; nf < 8; ++nf) {
                int cpr = nf * 16 + cl;
                facc4 v = acc[mf2][nf];
#pragma unroll
                for (int rr = 0; rr < 4; ++rr)
                    xl[(rowl + rr) * 132 + cpr] = fmaxf(v[rr], 0.0f);
            }
        }
    } else {
        ushort_t* Pp = P + (size_t)mp * PMpStr;
#pragma unroll
        for (int mf2 = 0; mf2 < 2; ++mf2) {
            int rowb = m0 + (wave_m * 2 + mf2) * 16 + rg * 4;
#pragma unroll
            for (int nf = 0; nf < 8; ++nf) {
                int cpr = nf * 16 + cl;
                facc4 v = acc[mf2][nf];
#pragma unroll
                for (int rr = 0; rr < 4; ++rr) {
                    int row = rowb + rr;
                    if (row < NN)
                        Pp[(size_t)(cpr >> 5) * (NN * 32) + (size_t)row * 32 + (cpr & 31)] = f2b(v[rr]);
                }
            }
        }
    }
    __syncthreads();
    // copy-out: nt fp32 out (full lines) + cached bf16 h1x (coalesced u64)
#pragma unroll
    for (int it = 0; it < 8; ++it) {
        int u = it * 512 + tid;                   // [0,4096)
        int seg = u >> 4, l16 = u & 15;
        int mp2 = seg >> 7, rowl = (seg >> 1) & 63, ch = seg & 1;
        int row = m0 + rowl;
        f32x4 v = *(f32x4*)((float*)lds + mp2 * (64 * 132) + rowl * 132 + ch * 64 + l16 * 4);
        if (row < NN) {
            __builtin_nontemporal_store(v,
                (f32x4*)(out + (size_t)mp2 * oMpStr + (size_t)row * 512 + ch * 128 + l16 * 4));
            *(u64*)(h1 + (size_t)mp2 * hMpStr + (size_t)row * 256 + ch * 128 + l16 * 4)
                = pack4(v[0], v[1], v[2], v[3]);
        }
    }
}

// ---------------------------------------------------------------------------
// Layer-2 projection: X = bf16 h1 [NN,256] via gload_lds (no pack VALU).
// wave_n=0: relu(X@Wx) -> overlay -> nt fp32 out at col 256.
// wave_n=1: X@Wn -> cached bf16 P sliced. Grid (GB, mp). 40KB LDS.
// ---------------------------------------------------------------------------
__global__ __launch_bounds__(256, 4)
void proj2_gemm(const ushort_t* __restrict__ X, size_t xMpStr,
                const ushort_t* __restrict__ W, size_t wMpStr,
                float* __restrict__ out, size_t oMpStr,
                ushort_t* __restrict__ P, size_t PMpStr)
{
    __shared__ bhalf8 lds[2560];
    const int tid = threadIdx.x;
    const int lane = tid & 63;
    const int wid = tid >> 6;
    const int wave_m = wid >> 1, wave_n = wid & 1;
    const int m0 = blockIdx.x * 64;
    const int mp = blockIdx.y;

    const ushort_t* Xp = X + (size_t)mp * xMpStr;
    const ushort_t* wx = W + (size_t)mp * wMpStr;
    const ushort_t* wn = wx + 4096 * 8;
    float* outp = out + (size_t)mp * oMpStr;
    ushort_t* Pp = P + (size_t)mp * PMpStr;

    facc4 acc[2][8];
    const facc4 z = {0.f, 0.f, 0.f, 0.f};
#pragma unroll
    for (int i = 0; i < 2; ++i)
#pragma unroll
        for (int j = 0; j < 8; ++j) acc[i][j] = z;

    for (int kt = 0; kt < 4; ++kt) {
        // ---- X stage: bf16 h1 direct to LDS frags ----
#pragma unroll
        for (int it = 0; it < 2; ++it) {
            int u = wid + it * 4;                // fragpos 0..7
            int mf = u & 3, ksl = u >> 2;
            int row = m0 + mf * 16 + (lane & 15); if (row > NN - 1) row = NN - 1;
            const ushort_t* src = Xp + (size_t)row * 256 + kt * 64 + ksl * 32 + ((lane >> 4) << 3);
            gload16(src, (char*)lds + (u * 64 + lane) * 16);
        }
        // ---- W stage ----
#pragma unroll
        for (int it = 0; it < 4; ++it) {
            int cb = (it * 4 + wid) * 64;        // [0,1024)
            gload16(wx + ((size_t)kt * 1024 + cb + lane) * 8,
                    (char*)lds + (512 + cb + lane) * 16);
            gload16(wn + ((size_t)kt * 1024 + cb + lane) * 8,
                    (char*)lds + (1536 + cb + lane) * 16);
        }
        __syncthreads();
        const int wB = wave_n ? 1536 : 512;
#pragma unroll
        for (int ksl = 0; ksl < 2; ++ksl) {
            bhalf8 a0 = lds[(ksl * 4 + wave_m * 2 + 0) * 64 + lane];
            bhalf8 a1 = lds[(ksl * 4 + wave_m * 2 + 1) * 64 + lane];
#pragma unroll
            for (int nf = 0; nf < 8; ++nf) {
                bhalf8 b = lds[wB + (ksl * 8 + nf) * 64 + lane];
                acc[0][nf] = __builtin_amdgcn_mfma_f32_16x16x32_bf16(a0, b, acc[0][nf], 0, 0, 0);
                acc[1][nf] = __builtin_amdgcn_mfma_f32_16x16x32_bf16(a1, b, acc[1][nf], 0, 0, 0);
            }
        }
        __syncthreads();
    }
    // ---- epilogue ----
    const int cl = lane & 15, rg = lane >> 4;
    float* xl = (float*)lds;                      // [64][132]
    if (wave_n == 0) {
#pragma unroll
        for (int mf2 = 0; mf2 < 2; ++mf2) {
            int rowl = (wave_m * 2 + mf2) * 16 + rg * 4;
#pragma unroll
            for (int nf = 0; nf < 8; ++nf) {
                int cpr = nf * 16 + cl;
                facc4 v = acc[mf2][nf];
#pragma unroll
                for (int rr = 0; rr < 4; ++rr)
                    xl[(rowl + rr) * 132 + cpr] = fmaxf(v[rr], 0.0f);
            }
        }
    } else {
#pragma unroll
        for (int mf2 = 0; mf2 < 2; ++mf2) {
            int rowb = m0 + (wave_m * 2 + mf2) * 16 + rg * 4;
#pragma unroll
            for (int nf = 0; nf < 8; ++nf) {
                int cpr = nf * 16 + cl;
                facc4 v = acc[mf2][nf];
#pragma unroll
                for (int rr = 0; rr < 4; ++rr) {
                    int row = rowb + rr;
                    if (row < NN)
                        Pp[(size_t)(cpr >> 5) * (NN * 32) + (size_t)row * 32 + (cpr & 31)] = f2b(v[rr]);
                }
            }
        }
    }
    __syncthreads();
#pragma unroll
    for (int j = 0; j < 4; ++j) {
        int rowl2 = wid * 16 + j * 4 + (lane >> 4);
        int row = m0 + rowl2;
#pragma unroll
        for (int c = 0; c < 2; ++c) {
            f32x4 v = *(f32x4*)&xl[rowl2 * 132 + c * 64 + cl * 4];
            if (row < NN)
                __builtin_nontemporal_store(v,
                    (f32x4*)&outp[(size_t)row * 512 + 256 + c * 128 + cl * 4]);
        }
    }
}

// ---------------------------------------------------------------------------
// XCD-pinned sliced gather + mean + relu. pair = blockIdx.x & 7 -> (slice,mp);
// each XCD owns one 3.2MB sub-table. nt-load neigh; cached P reads; LDS-staged
// full-line nt out stores. WRH1: also write bf16 h1n (cached, coalesced).
// ---------------------------------------------------------------------------
template<bool WRH1>
__global__ __launch_bounds__(256)
void gatherS(const ushort_t* __restrict__ P, size_t PMpStr,
             const int* __restrict__ nb, size_t nMpStr,
             float* __restrict__ out, size_t oMpStr, int obase,
             ushort_t* __restrict__ h1, size_t hMpStr)
{
    const int b = blockIdx.x;
    const int pair = b & 7;
    const int slice = pair & 3, mp = pair >> 2;
    const int nodeBase = (b >> 3) * 64;

    const ushort_t* Pp = P + (size_t)mp * PMpStr + (size_t)slice * (NN * 32);
    const int* nbp = nb + (size_t)mp * nMpStr;
    float* outp = out + (size_t)mp * oMpStr;

    __shared__ int nls[1024];
    __shared__ float og[64 * 36];
    {
        int i4 = nodeBase * 4 + threadIdx.x;
        int mx = NN * 4 - 1;
        if (i4 > mx) i4 = mx;
        i32x4 v = __builtin_nontemporal_load((const i32x4*)nbp + i4);
        ((i32x4*)nls)[threadIdx.x] = v;
    }
    __syncthreads();

    const int nl = threadIdx.x >> 2, q = threadIdx.x & 3;
    const int node = nodeBase + nl;
    const int* nr = nls + nl * SNEI;
    float a0=0.f,a1=0.f,a2=0.f,a3=0.f,a4=0.f,a5=0.f,a6=0.f,a7=0.f;
#pragma unroll
    for (int s = 0; s < SNEI; ++s) {
        u32x4 v = *(const u32x4*)(Pp + (size_t)nr[s] * 32 + q * 8);   // cached
        a0 += b2f(v.x & 0xFFFFu); a1 += b2f(v.x >> 16);
        a2 += b2f(v.y & 0xFFFFu); a3 += b2f(v.y >> 16);
        a4 += b2f(v.z & 0xFFFFu); a5 += b2f(v.z >> 16);
        a6 += b2f(v.w & 0xFFFFu); a7 += b2f(v.w >> 16);
    }
    const float M = 0.0625f;
    f32x4 r0 = { fmaxf(a0*M, 0.f), fmaxf(a1*M, 0.f), fmaxf(a2*M, 0.f), fmaxf(a3*M, 0.f) };
    f32x4 r1 = { fmaxf(a4*M, 0.f), fmaxf(a5*M, 0.f), fmaxf(a6*M, 0.f), fmaxf(a7*M, 0.f) };
    const int cco = (slice >> 1) * 128 + 64 + (slice & 1) * 32 + q * 8;
    if constexpr (WRH1) {
        if (node < NN) {
            ushort_t* hp = h1 + (size_t)mp * hMpStr + (size_t)node * 256 + cco;
            *(u64*)hp       = pack4(r0[0], r0[1], r0[2], r0[3]);
            *(u64*)(hp + 4) = pack4(r1[0], r1[1], r1[2], r1[3]);
        }
    }
    *(f32x4*)&og[nl * 36 + q * 8]     = r0;
    *(f32x4*)&og[nl * 36 + q * 8 + 4] = r1;
    __syncthreads();

    const int coff0 = (slice >> 1) * 128 + 64 + (slice & 1) * 32;
#pragma unroll
    for (int it = 0; it < 2; ++it) {
        int rl = it * 32 + (threadIdx.x >> 3), sub = threadIdx.x & 7;
        int nd = nodeBase + rl;
        f32x4 v = *(f32x4*)&og[rl * 36 + sub * 4];
        if (nd < NN)
            __builtin_nontemporal_store(v,
                (f32x4*)(outp + (size_t)nd * 512 + obase + coff0 + sub * 4));
    }
}

// ---------------------------------------------------------------------------
extern "C" void kernel_launch(void* const* d_in, const int* in_sizes, int n_in,
                              void* d_out, int out_size, void* d_ws, size_t ws_size,
                              hipStream_t stream)
{
    const float* feats  = (const float*)d_in[0];
    const float* prepWp = (const float*)d_in[1];
    const float* Wx1    = (const float*)d_in[2];
    const float* Wn1    = (const float*)d_in[3];
    const float* Wx2    = (const float*)d_in[4];
    const float* Wn2    = (const float*)d_in[5];
    const int*   neigh  = (const int*)d_in[6];
    float* out = (float*)d_out;
    ushort_t* ws = (ushort_t*)d_ws;

    const size_t permElems = 262144;                       // 512 KB
    ushort_t* perm = ws;
    ushort_t* P    = ws + permElems;                        // 2 * NN*128 bf16
    ushort_t* h1   = P + 2 * (size_t)NN * 128;              // 2 * NN*256 bf16

    const size_t PStr = (size_t)NN * 128;
    const size_t hStr = (size_t)NN * 256;
    const size_t oStr = (size_t)NN * 512;
    const size_t nStr = (size_t)NN * SNEI;
    const size_t wStr = (size_t)8192 * 8;

    permSetup<<<1024, 256, 0, stream>>>(prepWp, Wx1, Wn1, Wx2, Wn2, perm);

    // layer 1 (both mps fused): X = feats staged once per tile
    proj1_gemm<<<GB, 512, 0, stream>>>(feats, perm, wStr,
                                       out, oStr, h1, hStr, P, PStr);
    gatherS<true><<<GB * 8, 256, 0, stream>>>(P, PStr, neigh, nStr,
                                              out, oStr, 0, h1, hStr);
    // layer 2: X = bf16 h1 via gload_lds
    proj2_gemm<<<dim3(GB, 2), 256, 0, stream>>>(h1, hStr,
                                                perm + (size_t)16384 * 8, wStr,
                                                out, oStr, P, PStr);
    gatherS<false><<<GB * 8, 256, 0, stream>>>(P, PStr, neigh, nStr,
                                               out, oStr, 256, nullptr, 0);
}